// Round 16
// baseline (116.778 us; speedup 1.0000x reference)
//
#include <hip/hip_runtime.h>
#include <hip/hip_bf16.h>

#define BB 512
#define NN 714
#define EE 4096
#define ED2 62
#define CH 32
#define NT16 45    // ceil(NN/16)
#define NPAD 720   // NT16*16
#define VOCAB 38733
#define NCONV 2421 // ceil(VOCAB*16/256)
#define ELLR 432   // ELL row capacity (rows of 16 u16), rows per tile padded to x4
#define ELLB (ELLR*16)

typedef unsigned int u32;
typedef unsigned short u16;
typedef short short8 __attribute__((ext_vector_type(8)));
typedef float float4v __attribute__((ext_vector_type(4)));
typedef _Float16 f16x2 __attribute__((ext_vector_type(2)));
typedef __fp16 fp16x2 __attribute__((ext_vector_type(2)));

__device__ __forceinline__ u32 f2bf(float f) {
  u32 u = __float_as_uint(f);
  return (u + 0x7fffu + ((u >> 16) & 1u)) >> 16;
}
__device__ __forceinline__ u32 pack2(float a, float b) {
  return f2bf(a) | (f2bf(b) << 16);
}
__device__ __forceinline__ f16x2 u2h(u32 x) { union { u32 u; f16x2 h; } c; c.u = x; return c.h; }
__device__ __forceinline__ u32 packh(float a, float b) {
  union { fp16x2 h; u32 u; } c;
  c.h = __builtin_amdgcn_cvt_pkrtz(a, b);
  return c.u;
}

// y-in-LDS swizzle: uint4 slot q of node -> q ^ ((node>>1)&3).
// Note: yslot(r, kg) == yslot(r, 0) ^ kg  (kg<4 stays within the low 2 bits).
__device__ __forceinline__ int yslot(int node, int q) {
  return (node << 2) | (q ^ ((node >> 1) & 3));
}

// ---------------- Fused setup kernel: emb->bf16 table (blocks < NCONV) + per-batch prep ----------------
// ELL is stored TRANSPOSED per tile: entry (kk, col) at [base*16 + col*md4 + kk]
// so the aggregation loop reads 4 entries per ds_read_b64.
__global__ __launch_bounds__(256) void k_setup(const float* __restrict__ emb,
    uint2* __restrict__ embh, const int* __restrict__ edges,
    float* __restrict__ dinv, u16* __restrict__ perm_g,
    u16* __restrict__ ell_g, u16* __restrict__ elloff_g)
{
  const int tid = threadIdx.x;
  if (blockIdx.x < NCONV) {
    const int t = blockIdx.x * 256 + tid;
    if (t < VOCAB * 16) {
      const int row = t >> 4, c = (t & 15) * 4;
      const float* __restrict__ p = emb + (size_t)row * ED2;
      float v0 = (c + 0 < ED2) ? p[c + 0] : 0.f;
      float v1 = (c + 1 < ED2) ? p[c + 1] : 0.f;
      float v2 = (c + 2 < ED2) ? p[c + 2] : 0.f;
      float v3 = (c + 3 < ED2) ? p[c + 3] : 0.f;
      uint2 o = { pack2(v0, v1), pack2(v2, v3) };
      embh[t] = o;
    }
    return;
  }
  const int b = blockIdx.x - NCONV;
  const int* __restrict__ er = edges + (size_t)b * 2 * EE;       // e[0] = source (row)
  const int* __restrict__ ec = er + EE;                          // e[1] = target (col)
  __shared__ int s_cnt[NN];
  __shared__ int s_a[1024];
  __shared__ int s_b[1024];
  __shared__ u16 s_rows16[EE];
  __shared__ u16 s_perm[NPAD];
  __shared__ u16 s_degP[NPAD];
  __shared__ int s_hist[64];
  __shared__ int s_md[NT16 + 1];

  for (int i = tid; i < NN; i += 256) s_cnt[i] = 0;
  __syncthreads();
  for (int e = tid; e < EE; e += 256) atomicAdd(&s_cnt[ec[e]], 1);
  __syncthreads();
  for (int i = tid; i < 1024; i += 256) s_a[i] = (i < NN) ? s_cnt[i] : 0;
  for (int i = tid; i < NN; i += 256)
    dinv[(size_t)b * NN + i] = rsqrtf((float)(s_cnt[i] + 1));    // +1 self loop
  __syncthreads();
  int* src = s_a; int* dst = s_b;
  for (int d = 1; d < 1024; d <<= 1) {
    for (int i = tid; i < 1024; i += 256) {
      int v = src[i];
      if (i >= d) v += src[i - d];
      dst[i] = v;
    }
    __syncthreads();
    int* t = src; src = dst; dst = t;
  }
  // src (= s_a, 10 swaps) = inclusive scan of degree counts
  for (int i = tid; i < NN; i += 256) s_cnt[i] = 0;  // fill cursors
  __syncthreads();
  for (int e = tid; e < EE; e += 256) {
    int c = ec[e];
    int p = atomicAdd(&s_cnt[c], 1);
    int base = (c == 0) ? 0 : src[c - 1];
    s_rows16[base + p] = (u16)er[e];
  }
  // degree-sorted perm (counting sort, 64 bins)
  for (int i = tid; i < 64; i += 256) s_hist[i] = 0;
  for (int i = tid; i < NPAD; i += 256) { s_perm[i] = 0xFFFFu; s_degP[i] = 0; }
  __syncthreads();
  for (int i = tid; i < NN; i += 256) {
    int deg = src[i] - (i ? src[i - 1] : 0);
    atomicAdd(&s_hist[deg < 63 ? deg : 63], 1);
  }
  __syncthreads();
  if (tid == 0) {
    int run = 0;
    for (int j = 0; j < 64; ++j) { int c = s_hist[j]; s_hist[j] = run; run += c; }
  }
  __syncthreads();
  for (int i = tid; i < NN; i += 256) {
    int deg = src[i] - (i ? src[i - 1] : 0);
    int pos = atomicAdd(&s_hist[deg < 63 ? deg : 63], 1);
    s_perm[pos] = (u16)i;
    s_degP[pos] = (u16)deg;
  }
  __syncthreads();
  for (int i = tid; i < NPAD; i += 256) perm_g[(size_t)b * NPAD + i] = s_perm[i];
  // per-tile max degree, padded to multiple of 4
  if (tid < NT16) {
    int md = 0;
#pragma unroll
    for (int c = 0; c < 16; ++c) { int d = s_degP[tid * 16 + c]; md = d > md ? d : md; }
    s_md[tid] = (md + 3) & ~3;
  }
  __syncthreads();
  if (tid == 0) {
    int run = 0;
    for (int t = 0; t < NT16; ++t) {
      int m = s_md[t];
      if (run + m > ELLR) m = (ELLR - run) & ~3;   // capacity clamp (never expected)
      s_md[t] = run; run += m;
    }
    s_md[NT16] = run;
  }
  __syncthreads();
  if (tid <= NT16) elloff_g[(size_t)b * (NT16 + 1) + tid] = (u16)s_md[tid];
  // fill ELL, transposed, PRE-SWIZZLED entries e0 = yslot(r,0) (pad -> dummy node NN)
  u16* eg = ell_g + (size_t)b * ELLB;
  for (int t = 0; t < NT16; ++t) {
    const int base = s_md[t], md4 = s_md[t + 1] - base;
    for (int s = tid; s < md4 * 16; s += 256) {
      const int kk = s >> 4, col = s & 15;
      const int pv = s_perm[t * 16 + col];
      int r = NN;
      if (pv != 0xFFFF) {
        const int deg = s_degP[t * 16 + col];
        if (kk < deg) {
          const int off = pv ? src[pv - 1] : 0;
          r = (int)s_rows16[off + kk];
        }
      }
      eg[base * 16 + col * md4 + kk] = (u16)((r << 2) | ((r >> 1) & 3));
    }
  }
}

// ---------------- Kernel B: MFMA GCN1, 128-node chunks, 512 threads, fp16 y1 out ----------------
__global__ __launch_bounds__(512) void k_gcn1m(
    const int* __restrict__ ids, const float* __restrict__ cont,
    const uint4* __restrict__ embh, const float* __restrict__ W1,
    const float* __restrict__ dinv, u32* __restrict__ y1)
{
  const int bid = blockIdx.x;
  const int b = bid / 6, blk = bid - b * 6;
  const int base = blk * 128;
  const int nnodes = (NN - base < 128) ? (NN - base) : 128;
  const int nrows = nnodes * 2;
  const int tid = threadIdx.x, lane = tid & 63, wv = tid >> 6;   // wv 0..7
  const int col = lane & 15, kg = lane >> 4;

  __shared__ __align__(16) unsigned short sX[128 * 128];
  __shared__ float sC[128][4];
  __shared__ int s_ids[256];

  for (int t = tid; t < nnodes * 3; t += 512)
    sC[t / 3][t % 3] = cont[((size_t)b * NN + base) * 3 + t];
  if (tid < 256) s_ids[tid] = (tid < nrows) ? ids[((size_t)b * NN + base) * 2 + tid] : -1;
  __syncthreads();

  const int ck = tid & 7;
  const int rbase = tid >> 3;      // 0..63
  {
    uint4 w4[4];
#pragma unroll
    for (int q = 0; q < 4; ++q) {
      const int id = s_ids[q * 64 + rbase];
      if (id >= 0) w4[q] = embh[(size_t)id * 8 + ck];
      else { w4[q].x = 0; w4[q].y = 0; w4[q].z = 0; w4[q].w = 0; }
    }
#pragma unroll
    for (int q = 0; q < 4; ++q) {
      const int r = q * 64 + rbase;
      const int node = r >> 1, slot = r & 1;
      const int c16 = (node * 16 + slot * 8 + ck) ^ (node & 7);
      ((uint4*)sX)[c16] = w4[q];
    }
  }

  union { u32 u[4]; short8 v; } A[4][2];
#pragma unroll
  for (int kc = 0; kc < 4; ++kc)
#pragma unroll
    for (int hh = 0; hh < 2; ++hh)
#pragma unroll
      for (int jj = 0; jj < 4; ++jj) {
        const int k0 = kc * 32 + kg * 8 + 2 * jj;
        const int k1 = k0 + 1;
        const int m0 = (k0 < 62) ? k0 : ((k0 >= 64 && k0 < 126) ? k0 - 2 : -1);
        const int m1 = (k1 < 62) ? k1 : ((k1 >= 64 && k1 < 126) ? k1 - 2 : -1);
        const float wa = (m0 >= 0) ? W1[m0 * CH + hh * 16 + col] : 0.f;
        const float wb = (m1 >= 0) ? W1[m1 * CH + hh * 16 + col] : 0.f;
        A[kc][hh].u[jj] = pack2(wa, wb);
      }
  float Wc0[3][4], Wc1[3][4];
#pragma unroll
  for (int j = 0; j < 3; ++j)
#pragma unroll
    for (int reg = 0; reg < 4; ++reg) {
      Wc0[j][reg] = W1[(124 + j) * CH + 4 * kg + reg];
      Wc1[j][reg] = W1[(124 + j) * CH + 16 + 4 * kg + reg];
    }
  __syncthreads();

  const int ntiles = (nnodes + 15) >> 4;
  if (wv < ntiles) {
    const int ln = wv * 16 + col;
    float4v a0 = {0.f, 0.f, 0.f, 0.f}, a1 = {0.f, 0.f, 0.f, 0.f};
#pragma unroll
    for (int kc = 0; kc < 4; ++kc) {
      const int idx16 = (ln * 16 + kc * 4 + kg) ^ (ln & 7);
      short8 bf = *(const short8*)(sX + idx16 * 8);
      a0 = __builtin_amdgcn_mfma_f32_16x16x32_bf16(A[kc][0].v, bf, a0, 0, 0, 0);
      a1 = __builtin_amdgcn_mfma_f32_16x16x32_bf16(A[kc][1].v, bf, a1, 0, 0, 0);
    }
#pragma unroll
    for (int j = 0; j < 3; ++j) {
      const float cv = sC[ln][j];
#pragma unroll
      for (int reg = 0; reg < 4; ++reg) {
        a0[reg] = fmaf(cv, Wc0[j][reg], a0[reg]);
        a1[reg] = fmaf(cv, Wc1[j][reg], a1[reg]);
      }
    }
    if (ln < nnodes) {
      const int gnode = base + ln;
      const float dv = dinv[(size_t)b * NN + gnode];
      u32* op = y1 + ((size_t)b * NN + gnode) * 16;
      uint2 s0 = { packh(a0[0] * dv, a0[1] * dv), packh(a0[2] * dv, a0[3] * dv) };
      uint2 s1 = { packh(a1[0] * dv, a1[1] * dv), packh(a1[2] * dv, a1[3] * dv) };
      *(uint2*)(op + 2 * kg) = s0;
      *(uint2*)(op + 8 + 2 * kg) = s1;
    }
  }
}

// ---------------- Fused kernel: layers 2,3,4 + tail ----------------
// y in LDS is fp16; aggregation via v_pk_add_f16 with f32 flush every 16 edges.
// ELL transposed: 4 pre-swizzled entries per ds_read_b64; a16 = e ^ kg.
#define GATHER(A16) { uint4 n = sy4[(A16)]; \
  a0h += u2h(n.x); a1h += u2h(n.y); a2h += u2h(n.z); a3h += u2h(n.w); }
#define EDGE4(EP, K) { uint2 ee = *(const uint2*)((EP) + (K)); \
  GATHER(((int)(ee.x & 0xffffu)) ^ kg) \
  GATHER(((int)(ee.x >> 16)) ^ kg) \
  GATHER(((int)(ee.y & 0xffffu)) ^ kg) \
  GATHER(((int)(ee.y >> 16)) ^ kg) }
#define FLUSH { zx[0] += (float)a0h.x; zx[1] += (float)a0h.y; \
  zx[2] += (float)a1h.x; zx[3] += (float)a1h.y; \
  zx[4] += (float)a2h.x; zx[5] += (float)a2h.y; \
  zx[6] += (float)a3h.x; zx[7] += (float)a3h.y; \
  a0h = hz; a1h = hz; a2h = hz; a3h = hz; }
#define AGG_LOOP(EP) { int kk = 0; \
  while (kk + 16 <= md4) { \
    EDGE4(EP, kk) EDGE4(EP, kk + 4) EDGE4(EP, kk + 8) EDGE4(EP, kk + 12) \
    FLUSH \
    kk += 16; } \
  if (kk < md4) { \
    for (; kk < md4; kk += 4) EDGE4(EP, kk) \
    FLUSH } }

template<int ACT>
__device__ __forceinline__ void gcn_pass32(
    u32* __restrict__ sy, const u16* __restrict__ s_ell,
    const u16* __restrict__ s_elloff, const float* __restrict__ s_dv,
    const u16* __restrict__ pvs,
    const int wv, const int col, const int kg,
    const short8 a0v, const short8 a1v, const float* __restrict__ bias8)
{
  const uint4* sy4 = (const uint4*)sy;
  const f16x2 hz = {(_Float16)0, (_Float16)0};
  u32 outs[3][4];
  int nodes[3];
#pragma unroll
  for (int p = 0; p < 3; ++p) {
    const int t = p * 16 + wv;
    const int pv = (t < NT16) ? (int)pvs[p] : 0xFFFF;
    const int node = (pv == 0xFFFF) ? NN : pv;
    nodes[p] = (pv == 0xFFFF) ? -1 : pv;
    int base = 0, md4 = 0;
    if (t < NT16) { base = s_elloff[t]; md4 = s_elloff[t + 1] - base; }
    base = __builtin_amdgcn_readfirstlane(base);
    md4 = __builtin_amdgcn_readfirstlane(md4);
    f16x2 a0h, a1h, a2h, a3h;
    {
      uint4 u = sy4[yslot(node, kg)];          // self (dummy row = zeros)
      a0h = u2h(u.x); a1h = u2h(u.y); a2h = u2h(u.z); a3h = u2h(u.w);
    }
    float zx[8];
#pragma unroll
    for (int j = 0; j < 8; ++j) zx[j] = 0.f;
    const u16* ep = s_ell + base * 16 + col * md4;
    AGG_LOOP(ep)
    const float dv = s_dv[node];               // dummy dv = 0
    float h[8];
#pragma unroll
    for (int j = 0; j < 8; ++j) {
      float t2 = fmaf(dv, zx[j], bias8[j]);
      float l = (t2 > 0.f) ? t2 : 0.01f * t2;
      h[j] = (ACT == 0) ? l : (l + t2);
    }
    union { u32 u[4]; short8 v; } ub;
#pragma unroll
    for (int jj = 0; jj < 4; ++jj) ub.u[jj] = pack2(h[2 * jj], h[2 * jj + 1]);
    float4v z4 = {0.f, 0.f, 0.f, 0.f};
    float4v d0 = __builtin_amdgcn_mfma_f32_16x16x32_bf16(a0v, ub.v, z4, 0, 0, 0);
    float4v d1 = __builtin_amdgcn_mfma_f32_16x16x32_bf16(a1v, ub.v, z4, 0, 0, 0);
    outs[p][0] = packh(d0[0] * dv, d0[1] * dv);
    outs[p][1] = packh(d0[2] * dv, d0[3] * dv);
    outs[p][2] = packh(d1[0] * dv, d1[1] * dv);
    outs[p][3] = packh(d1[2] * dv, d1[3] * dv);
  }
  __syncthreads();
#pragma unroll
  for (int p = 0; p < 3; ++p) {
    const int node = nodes[p];
    if (node >= 0) {
      const int sw = (node >> 1) & 3;
      u32* op = sy + node * 16;
      uint2 s0 = { outs[p][0], outs[p][1] };
      uint2 s1 = { outs[p][2], outs[p][3] };
      *(uint2*)(op + (((kg >> 1) ^ sw) << 2) + ((2 * kg) & 3)) = s0;
      *(uint2*)(op + (((2 + (kg >> 1)) ^ sw) << 2) + ((2 * kg) & 3)) = s1;
    }
  }
  __syncthreads();
}

__global__ __launch_bounds__(1024) void k_fused(
    const u32* __restrict__ yin, const float* __restrict__ dinv,
    const u16* __restrict__ perm_g, const u16* __restrict__ ell_g,
    const u16* __restrict__ elloff_g,
    const float* __restrict__ b1, const float* __restrict__ W2,
    const float* __restrict__ b2, const float* __restrict__ W3,
    const float* __restrict__ b3, const float* __restrict__ W4,
    const float* __restrict__ b4, const float* __restrict__ Wf1,
    const float* __restrict__ bf1, const float* __restrict__ Wf2,
    const float* __restrict__ bf2, float* __restrict__ out)
{
  const int b = blockIdx.x;
  const int tid = threadIdx.x;
  const int lane = tid & 63;
  const int wv = tid >> 6;          // wave 0..15
  const int col = lane & 15;
  const int kg = lane >> 4;

  __shared__ __align__(16) char smem[65408];
  u32*   s_y      = (u32*)smem;                     // 45760 B (715 rows; dead later)
  u16*   s_ell    = (u16*)(smem + 45760);           // 13824
  u16*   s_elloff = (u16*)(smem + 59584);           // 96
  float* s_dv     = (float*)(smem + 59680);         // 2864 (incl dummy)
  float* s_h      = (float*)(smem + 62544);         // 2864 (incl dummy)
  float* s_red    = (float*)smem;                   // aliases dead s_y
  float* s_u      = (float*)(smem + 8192);          // aliases dead s_y

  {
    const uint4* __restrict__ ysrc = (const uint4*)(yin + (size_t)b * NN * 16);
    uint4* sy4w = (uint4*)s_y;
    const uint4 z4 = {0, 0, 0, 0};
    for (int s = tid; s < (NN + 1) * 4; s += 1024) {
      const int node = s >> 2;
      sy4w[yslot(node, s & 3)] = (node < NN) ? ysrc[s] : z4;
    }
    const uint4* __restrict__ esrc = (const uint4*)(ell_g + (size_t)b * ELLB);
    uint4* ed = (uint4*)s_ell;
    for (int s = tid; s < ELLB / 8; s += 1024) ed[s] = esrc[s];
    for (int i = tid; i <= NT16; i += 1024) s_elloff[i] = elloff_g[(size_t)b * (NT16 + 1) + i];
    for (int i = tid; i < NN; i += 1024) s_dv[i] = dinv[(size_t)b * NN + i];
    if (tid == 1023) s_dv[NN] = 0.f;
  }
  u16 pvs[3];
#pragma unroll
  for (int p = 0; p < 3; ++p) {
    const int t = p * 16 + wv;
    pvs[p] = (t < NT16) ? perm_g[(size_t)b * NPAD + t * 16 + col] : (u16)0xFFFF;
  }
  const u16 pvt = (tid < NPAD) ? perm_g[(size_t)b * NPAD + tid] : (u16)0xFFFF;

  union { u32 u[4]; short8 v; } uaA0, uaA1, uaB0, uaB1;
#pragma unroll
  for (int jj = 0; jj < 4; ++jj) {
    uaA0.u[jj] = pack2(W2[(kg * 8 + 2 * jj) * CH + col],      W2[(kg * 8 + 2 * jj + 1) * CH + col]);
    uaA1.u[jj] = pack2(W2[(kg * 8 + 2 * jj) * CH + 16 + col], W2[(kg * 8 + 2 * jj + 1) * CH + 16 + col]);
    uaB0.u[jj] = pack2(W3[(kg * 8 + 2 * jj) * CH + col],      W3[(kg * 8 + 2 * jj + 1) * CH + col]);
    uaB1.u[jj] = pack2(W3[(kg * 8 + 2 * jj) * CH + 16 + col], W3[(kg * 8 + 2 * jj + 1) * CH + 16 + col]);
  }
  float b1r[8], b2r[8], b3r[8], w4r[8];
#pragma unroll
  for (int j = 0; j < 8; ++j) {
    b1r[j] = b1[kg * 8 + j];
    b2r[j] = b2[kg * 8 + j];
    b3r[j] = b3[kg * 8 + j];
    w4r[j] = W4[kg * 8 + j];
  }
  const float bb4 = b4[0];
  __syncthreads();

  gcn_pass32<0>(s_y, s_ell, s_elloff, s_dv, pvs, wv, col, kg, uaA0.v, uaA1.v, b1r);
  gcn_pass32<1>(s_y, s_ell, s_elloff, s_dv, pvs, wv, col, kg, uaB0.v, uaB1.v, b2r);

  // layer 4: agg + b3, lrelu+t, dot W4 (32->1), *dinv -> s_h
  {
    const uint4* sy4 = (const uint4*)s_y;
    const f16x2 hz = {(_Float16)0, (_Float16)0};
#pragma unroll
    for (int p = 0; p < 3; ++p) {
      const int t = p * 16 + wv;
      const int pv = (t < NT16) ? (int)pvs[p] : 0xFFFF;
      const int node = (pv == 0xFFFF) ? NN : pv;
      int base = 0, md4 = 0;
      if (t < NT16) { base = s_elloff[t]; md4 = s_elloff[t + 1] - base; }
      base = __builtin_amdgcn_readfirstlane(base);
      md4 = __builtin_amdgcn_readfirstlane(md4);
      f16x2 a0h, a1h, a2h, a3h;
      {
        uint4 u = sy4[yslot(node, kg)];
        a0h = u2h(u.x); a1h = u2h(u.y); a2h = u2h(u.z); a3h = u2h(u.w);
      }
      float zx[8];
#pragma unroll
      for (int j = 0; j < 8; ++j) zx[j] = 0.f;
      const u16* ep = s_ell + base * 16 + col * md4;
      AGG_LOOP(ep)
      const float dv = s_dv[node];
      float part = 0.f;
#pragma unroll
      for (int j = 0; j < 8; ++j) {
        float t2 = fmaf(dv, zx[j], b3r[j]);
        float l = (t2 > 0.f) ? t2 : 0.01f * t2;
        part = fmaf(l + t2, w4r[j], part);
      }
      part += __shfl_xor(part, 16, 64);
      part += __shfl_xor(part, 32, 64);
      if (pv != 0xFFFF && kg == 0) s_h[node] = part * dv;
    }
  }
  __syncthreads();
  if (tid == 1023) s_h[NN] = 0.f;
  __syncthreads();

  // tail aggregation via transposed ELL: z = h[node] + sum h[e>>2]; lrelu(dinv*z + b4)
  {
    float hval = 0.f;
    int node = -1;
    if (tid < NPAD && pvt != 0xFFFF) {
      node = (int)pvt;
      const int t = tid >> 4, c = tid & 15;
      const int base = s_elloff[t], md4 = s_elloff[t + 1] - base;
      float z = s_h[node];
      const u16* ep = s_ell + base * 16 + c * md4;
      for (int kk = 0; kk < md4; ++kk) z += s_h[((int)ep[kk]) >> 2];
      float t2 = fmaf(s_dv[node], z, bb4);
      hval = (t2 > 0.f) ? t2 : 0.01f * t2;
    }
    __syncthreads();
    if (node >= 0) s_h[node] = hval;
  }
  __syncthreads();

  // FC1: 714 -> 128, 8-way split-K
  const int j = tid & 127, q = tid >> 7;
  {
    const int n0 = (q * NN) >> 3, n1 = ((q + 1) * NN) >> 3;
    const float* __restrict__ w = Wf1 + j;
    float a0 = 0.f, a1 = 0.f;
    int n = n0;
#pragma unroll 4
    for (; n + 2 <= n1; n += 2) {
      a0 = fmaf(s_h[n], w[(size_t)n * 128], a0);
      a1 = fmaf(s_h[n + 1], w[(size_t)(n + 1) * 128], a1);
    }
    if (n < n1) a0 = fmaf(s_h[n], w[(size_t)n * 128], a0);
    s_red[tid] = a0 + a1;
  }
  __syncthreads();
  if (tid < 128) {
    float v = bf1[tid];
#pragma unroll
    for (int m = 0; m < 8; ++m) v += s_red[tid + 128 * m];
    s_u[tid] = fmaxf(v, 0.f);
  }
  __syncthreads();
  // FC2: 128 -> 128, 8-way split-K
  {
    const float* __restrict__ w = Wf2 + j;
    float a0 = 0.f, a1 = 0.f;
#pragma unroll
    for (int k = q * 16; k < q * 16 + 16; k += 2) {
      a0 = fmaf(s_u[k], w[(size_t)k * 128], a0);
      a1 = fmaf(s_u[k + 1], w[(size_t)(k + 1) * 128], a1);
    }
    s_red[tid] = a0 + a1;
  }
  __syncthreads();
  if (tid < 128) {
    float v = bf2[tid];
#pragma unroll
    for (int m = 0; m < 8; ++m) v += s_red[tid + 128 * m];
    out[(size_t)b * 128 + tid] = fmaxf(v, 0.f);
  }
}

extern "C" void kernel_launch(void* const* d_in, const int* in_sizes, int n_in,
                              void* d_out, int out_size, void* d_ws, size_t ws_size,
                              hipStream_t stream)
{
  (void)in_sizes; (void)n_in; (void)out_size; (void)ws_size;
  const int*   ids  = (const int*)d_in[0];
  const float* cont = (const float*)d_in[1];
  const int*   edges= (const int*)d_in[2];
  const float* emb  = (const float*)d_in[3];
  const float* W1   = (const float*)d_in[4];
  const float* b1   = (const float*)d_in[5];
  const float* W2   = (const float*)d_in[6];
  const float* b2   = (const float*)d_in[7];
  const float* W3   = (const float*)d_in[8];
  const float* b3   = (const float*)d_in[9];
  const float* W4   = (const float*)d_in[10];
  const float* b4   = (const float*)d_in[11];
  const float* Wf1  = (const float*)d_in[12];
  const float* bf1  = (const float*)d_in[13];
  const float* Wf2  = (const float*)d_in[14];
  const float* bf2  = (const float*)d_in[15];
  float* out = (float*)d_out;

  char* ws = (char*)d_ws;
  size_t off = 0;
  auto alloc = [&](size_t bytes) -> void* {
    void* p = ws + off;
    off = (off + bytes + 255) & ~(size_t)255;
    return p;
  };
  float* dinv     = (float*)alloc((size_t)BB * NN * 4);
  u16*   perm     = (u16*)  alloc((size_t)BB * NPAD * 2);
  u16*   ell      = (u16*)  alloc((size_t)BB * ELLB * 2);
  u16*   elloff   = (u16*)  alloc((size_t)BB * (NT16 + 1) * 2);
  uint2* embh     = (uint2*)alloc((size_t)VOCAB * 64 * 2);
  u32*   yA       = (u32*)  alloc((size_t)BB * NN * 16 * 4);

  hipLaunchKernelGGL(k_setup, dim3(NCONV + BB), dim3(256), 0, stream,
                     emb, embh, edges, dinv, perm, ell, elloff);
  hipLaunchKernelGGL(k_gcn1m, dim3(BB * 6), dim3(512), 0, stream,
                     ids, cont, (const uint4*)embh, W1, dinv, yA);
  hipLaunchKernelGGL(k_fused, dim3(BB), dim3(1024), 0, stream,
                     yA, dinv, perm, ell, elloff,
                     b1, W2, b2, W3, b3, W4, b4, Wf1, bf1, Wf2, bf2, out);
}

// Round 17
// 110.341 us; speedup vs baseline: 1.0583x; 1.0583x over previous
//
#include <hip/hip_runtime.h>
#include <hip/hip_bf16.h>

#define BB 512
#define NN 714
#define EE 4096
#define ED2 62
#define CH 32
#define NT16 45    // ceil(NN/16)
#define NPAD 720   // NT16*16
#define VOCAB 38733
#define NCONV 2421 // ceil(VOCAB*16/256)
#define ELLR 432   // ELL row capacity (rows of 16 u16), rows per tile padded to x4
#define ELLB (ELLR*16)

typedef unsigned int u32;
typedef unsigned short u16;
typedef short short8 __attribute__((ext_vector_type(8)));
typedef float float4v __attribute__((ext_vector_type(4)));
typedef _Float16 f16x2 __attribute__((ext_vector_type(2)));
typedef __fp16 fp16x2 __attribute__((ext_vector_type(2)));

__device__ __forceinline__ u32 f2bf(float f) {
  u32 u = __float_as_uint(f);
  return (u + 0x7fffu + ((u >> 16) & 1u)) >> 16;
}
__device__ __forceinline__ u32 pack2(float a, float b) {
  return f2bf(a) | (f2bf(b) << 16);
}
__device__ __forceinline__ f16x2 u2h(u32 x) { union { u32 u; f16x2 h; } c; c.u = x; return c.h; }
__device__ __forceinline__ u32 packh(float a, float b) {
  union { fp16x2 h; u32 u; } c;
  c.h = __builtin_amdgcn_cvt_pkrtz(a, b);
  return c.u;
}

// y-in-LDS swizzle: uint4 slot q of node -> q ^ ((node>>1)&3).
// Note: yslot(r, kg) == yslot(r, 0) ^ kg  (kg<4 stays within the low 2 bits).
__device__ __forceinline__ int yslot(int node, int q) {
  return (node << 2) | (q ^ ((node >> 1) & 3));
}

// ---------------- Fused setup kernel: emb->bf16 table (blocks < NCONV) + per-batch prep ----------------
__global__ __launch_bounds__(256) void k_setup(const float* __restrict__ emb,
    uint2* __restrict__ embh, const int* __restrict__ edges,
    float* __restrict__ dinv, u16* __restrict__ perm_g,
    u16* __restrict__ ell_g, u16* __restrict__ elloff_g)
{
  const int tid = threadIdx.x;
  if (blockIdx.x < NCONV) {
    const int t = blockIdx.x * 256 + tid;
    if (t < VOCAB * 16) {
      const int row = t >> 4, c = (t & 15) * 4;
      const float* __restrict__ p = emb + (size_t)row * ED2;
      float v0 = (c + 0 < ED2) ? p[c + 0] : 0.f;
      float v1 = (c + 1 < ED2) ? p[c + 1] : 0.f;
      float v2 = (c + 2 < ED2) ? p[c + 2] : 0.f;
      float v3 = (c + 3 < ED2) ? p[c + 3] : 0.f;
      uint2 o = { pack2(v0, v1), pack2(v2, v3) };
      embh[t] = o;
    }
    return;
  }
  const int b = blockIdx.x - NCONV;
  const int* __restrict__ er = edges + (size_t)b * 2 * EE;       // e[0] = source (row)
  const int* __restrict__ ec = er + EE;                          // e[1] = target (col)
  __shared__ int s_cnt[NN];
  __shared__ int s_a[1024];
  __shared__ int s_b[1024];
  __shared__ u16 s_rows16[EE];
  __shared__ u16 s_perm[NPAD];
  __shared__ u16 s_degP[NPAD];
  __shared__ int s_hist[64];
  __shared__ int s_md[NT16 + 1];

  for (int i = tid; i < NN; i += 256) s_cnt[i] = 0;
  __syncthreads();
  for (int e = tid; e < EE; e += 256) atomicAdd(&s_cnt[ec[e]], 1);
  __syncthreads();
  for (int i = tid; i < 1024; i += 256) s_a[i] = (i < NN) ? s_cnt[i] : 0;
  for (int i = tid; i < NN; i += 256)
    dinv[(size_t)b * NN + i] = rsqrtf((float)(s_cnt[i] + 1));    // +1 self loop
  __syncthreads();
  int* src = s_a; int* dst = s_b;
  for (int d = 1; d < 1024; d <<= 1) {
    for (int i = tid; i < 1024; i += 256) {
      int v = src[i];
      if (i >= d) v += src[i - d];
      dst[i] = v;
    }
    __syncthreads();
    int* t = src; src = dst; dst = t;
  }
  // src (= s_a, 10 swaps) = inclusive scan of degree counts
  for (int i = tid; i < NN; i += 256) s_cnt[i] = 0;  // fill cursors
  __syncthreads();
  for (int e = tid; e < EE; e += 256) {
    int c = ec[e];
    int p = atomicAdd(&s_cnt[c], 1);
    int base = (c == 0) ? 0 : src[c - 1];
    s_rows16[base + p] = (u16)er[e];
  }
  // degree-sorted perm (counting sort, 64 bins)
  for (int i = tid; i < 64; i += 256) s_hist[i] = 0;
  for (int i = tid; i < NPAD; i += 256) { s_perm[i] = 0xFFFFu; s_degP[i] = 0; }
  __syncthreads();
  for (int i = tid; i < NN; i += 256) {
    int deg = src[i] - (i ? src[i - 1] : 0);
    atomicAdd(&s_hist[deg < 63 ? deg : 63], 1);
  }
  __syncthreads();
  if (tid == 0) {
    int run = 0;
    for (int j = 0; j < 64; ++j) { int c = s_hist[j]; s_hist[j] = run; run += c; }
  }
  __syncthreads();
  for (int i = tid; i < NN; i += 256) {
    int deg = src[i] - (i ? src[i - 1] : 0);
    int pos = atomicAdd(&s_hist[deg < 63 ? deg : 63], 1);
    s_perm[pos] = (u16)i;
    s_degP[pos] = (u16)deg;
  }
  __syncthreads();
  for (int i = tid; i < NPAD; i += 256) perm_g[(size_t)b * NPAD + i] = s_perm[i];
  // per-tile max degree, padded to multiple of 4
  if (tid < NT16) {
    int md = 0;
#pragma unroll
    for (int c = 0; c < 16; ++c) { int d = s_degP[tid * 16 + c]; md = d > md ? d : md; }
    s_md[tid] = (md + 3) & ~3;
  }
  __syncthreads();
  if (tid == 0) {
    int run = 0;
    for (int t = 0; t < NT16; ++t) {
      int m = s_md[t];
      if (run + m > ELLR) m = (ELLR - run) & ~3;   // capacity clamp (never expected)
      s_md[t] = run; run += m;
    }
    s_md[NT16] = run;
  }
  __syncthreads();
  if (tid <= NT16) elloff_g[(size_t)b * (NT16 + 1) + tid] = (u16)s_md[tid];
  // fill ELL with PRE-SWIZZLED entries e0 = yslot(r,0) (pad -> dummy node NN)
  u16* eg = ell_g + (size_t)b * ELLB;
  for (int t = 0; t < NT16; ++t) {
    const int base = s_md[t], md4 = s_md[t + 1] - base;
    for (int s = tid; s < md4 * 16; s += 256) {
      const int kk = s >> 4, col = s & 15;
      const int pv = s_perm[t * 16 + col];
      int r = NN;
      if (pv != 0xFFFF) {
        const int deg = s_degP[t * 16 + col];
        if (kk < deg) {
          const int off = pv ? src[pv - 1] : 0;
          r = (int)s_rows16[off + kk];
        }
      }
      eg[base * 16 + s] = (u16)((r << 2) | ((r >> 1) & 3));
    }
  }
}

// ---------------- Kernel B: MFMA GCN1, 128-node chunks, 256 threads, fp16 y1 out ----------------
__global__ __launch_bounds__(256) void k_gcn1m(
    const int* __restrict__ ids, const float* __restrict__ cont,
    const uint4* __restrict__ embh, const float* __restrict__ W1,
    const float* __restrict__ dinv, u32* __restrict__ y1)
{
  const int bid = blockIdx.x;
  const int b = bid / 6, blk = bid - b * 6;
  const int base = blk * 128;
  const int nnodes = (NN - base < 128) ? (NN - base) : 128;
  const int nrows = nnodes * 2;
  const int tid = threadIdx.x, lane = tid & 63, wv = tid >> 6;
  const int col = lane & 15, kg = lane >> 4;

  __shared__ __align__(16) unsigned short sX[128 * 128];
  __shared__ float sC[128][4];
  __shared__ int s_ids[256];

  for (int t = tid; t < nnodes * 3; t += 256)
    sC[t / 3][t % 3] = cont[((size_t)b * NN + base) * 3 + t];
  s_ids[tid] = (tid < nrows) ? ids[((size_t)b * NN + base) * 2 + tid] : -1;
  __syncthreads();

  const int ck = tid & 7;
  const int rbase = tid >> 3;
  {
    uint4 w4[8];
#pragma unroll
    for (int q = 0; q < 8; ++q) {
      const int id = s_ids[q * 32 + rbase];
      if (id >= 0) w4[q] = embh[(size_t)id * 8 + ck];
      else { w4[q].x = 0; w4[q].y = 0; w4[q].z = 0; w4[q].w = 0; }
    }
#pragma unroll
    for (int q = 0; q < 8; ++q) {
      const int r = q * 32 + rbase;
      const int node = r >> 1, slot = r & 1;
      const int c16 = (node * 16 + slot * 8 + ck) ^ (node & 7);
      ((uint4*)sX)[c16] = w4[q];
    }
  }

  union { u32 u[4]; short8 v; } A[4][2];
#pragma unroll
  for (int kc = 0; kc < 4; ++kc)
#pragma unroll
    for (int hh = 0; hh < 2; ++hh)
#pragma unroll
      for (int jj = 0; jj < 4; ++jj) {
        const int k0 = kc * 32 + kg * 8 + 2 * jj;
        const int k1 = k0 + 1;
        const int m0 = (k0 < 62) ? k0 : ((k0 >= 64 && k0 < 126) ? k0 - 2 : -1);
        const int m1 = (k1 < 62) ? k1 : ((k1 >= 64 && k1 < 126) ? k1 - 2 : -1);
        const float wa = (m0 >= 0) ? W1[m0 * CH + hh * 16 + col] : 0.f;
        const float wb = (m1 >= 0) ? W1[m1 * CH + hh * 16 + col] : 0.f;
        A[kc][hh].u[jj] = pack2(wa, wb);
      }
  float Wc0[3][4], Wc1[3][4];
#pragma unroll
  for (int j = 0; j < 3; ++j)
#pragma unroll
    for (int reg = 0; reg < 4; ++reg) {
      Wc0[j][reg] = W1[(124 + j) * CH + 4 * kg + reg];
      Wc1[j][reg] = W1[(124 + j) * CH + 16 + 4 * kg + reg];
    }
  __syncthreads();

  const int ntiles = (nnodes + 15) >> 4;
  for (int t = wv; t < ntiles; t += 4) {
    const int ln = t * 16 + col;
    float4v a0 = {0.f, 0.f, 0.f, 0.f}, a1 = {0.f, 0.f, 0.f, 0.f};
#pragma unroll
    for (int kc = 0; kc < 4; ++kc) {
      const int idx16 = (ln * 16 + kc * 4 + kg) ^ (ln & 7);
      short8 bf = *(const short8*)(sX + idx16 * 8);
      a0 = __builtin_amdgcn_mfma_f32_16x16x32_bf16(A[kc][0].v, bf, a0, 0, 0, 0);
      a1 = __builtin_amdgcn_mfma_f32_16x16x32_bf16(A[kc][1].v, bf, a1, 0, 0, 0);
    }
#pragma unroll
    for (int j = 0; j < 3; ++j) {
      const float cv = sC[ln][j];
#pragma unroll
      for (int reg = 0; reg < 4; ++reg) {
        a0[reg] = fmaf(cv, Wc0[j][reg], a0[reg]);
        a1[reg] = fmaf(cv, Wc1[j][reg], a1[reg]);
      }
    }
    if (ln < nnodes) {
      const int gnode = base + ln;
      const float dv = dinv[(size_t)b * NN + gnode];
      u32* op = y1 + ((size_t)b * NN + gnode) * 16;
      uint2 s0 = { packh(a0[0] * dv, a0[1] * dv), packh(a0[2] * dv, a0[3] * dv) };
      uint2 s1 = { packh(a1[0] * dv, a1[1] * dv), packh(a1[2] * dv, a1[3] * dv) };
      *(uint2*)(op + 2 * kg) = s0;
      *(uint2*)(op + 8 + 2 * kg) = s1;
    }
  }
}

// ---------------- Fused kernel: layers 2,3,4 + tail ----------------
// y in LDS is fp16; aggregation via v_pk_add_f16 with f32 flush every 16 edges.
// ELL entries are pre-swizzled: a16 = e0 ^ kg (1 VALU instead of 5).
#define EDGE(EP, K) { const int a16 = ((int)(EP)[(K) * 16]) ^ kg; \
  uint4 n = sy4[a16]; \
  a0h += u2h(n.x); a1h += u2h(n.y); a2h += u2h(n.z); a3h += u2h(n.w); }
#define FLUSH { zx[0] += (float)a0h.x; zx[1] += (float)a0h.y; \
  zx[2] += (float)a1h.x; zx[3] += (float)a1h.y; \
  zx[4] += (float)a2h.x; zx[5] += (float)a2h.y; \
  zx[6] += (float)a3h.x; zx[7] += (float)a3h.y; \
  a0h = hz; a1h = hz; a2h = hz; a3h = hz; }
#define AGG_LOOP(EP) { int kk = 0; \
  while (kk + 16 <= md4) { \
    _Pragma("unroll") for (int e = 0; e < 16; ++e) EDGE(EP, kk + e) \
    FLUSH \
    kk += 16; } \
  if (kk + 8 <= md4) { \
    _Pragma("unroll") for (int e = 0; e < 8; ++e) EDGE(EP, kk + e) \
    FLUSH \
    kk += 8; } \
  if (kk < md4) { \
    _Pragma("unroll") for (int e = 0; e < 4; ++e) EDGE(EP, kk + e) \
    FLUSH } }

template<int ACT>
__device__ __forceinline__ void gcn_pass32(
    u32* __restrict__ sy, const u16* __restrict__ s_ell,
    const u16* __restrict__ s_elloff, const float* __restrict__ s_dv,
    const u16* __restrict__ pvs,
    const int wv, const int col, const int kg,
    const short8 a0v, const short8 a1v, const float* __restrict__ bias8)
{
  const uint4* sy4 = (const uint4*)sy;
  const f16x2 hz = {(_Float16)0, (_Float16)0};
  u32 outs[3][4];
  int nodes[3];
#pragma unroll
  for (int p = 0; p < 3; ++p) {
    const int t = p * 16 + wv;
    const int pv = (t < NT16) ? (int)pvs[p] : 0xFFFF;
    const int node = (pv == 0xFFFF) ? NN : pv;
    nodes[p] = (pv == 0xFFFF) ? -1 : pv;
    int base = 0, md4 = 0;
    if (t < NT16) { base = s_elloff[t]; md4 = s_elloff[t + 1] - base; }
    base = __builtin_amdgcn_readfirstlane(base);
    md4 = __builtin_amdgcn_readfirstlane(md4);
    f16x2 a0h, a1h, a2h, a3h;
    {
      uint4 u = sy4[yslot(node, kg)];          // self (dummy row = zeros)
      a0h = u2h(u.x); a1h = u2h(u.y); a2h = u2h(u.z); a3h = u2h(u.w);
    }
    float zx[8];
#pragma unroll
    for (int j = 0; j < 8; ++j) zx[j] = 0.f;
    const u16* ep = s_ell + base * 16 + col;
    AGG_LOOP(ep)
    const float dv = s_dv[node];               // dummy dv = 0
    float h[8];
#pragma unroll
    for (int j = 0; j < 8; ++j) {
      float t2 = fmaf(dv, zx[j], bias8[j]);
      float l = (t2 > 0.f) ? t2 : 0.01f * t2;
      h[j] = (ACT == 0) ? l : (l + t2);
    }
    union { u32 u[4]; short8 v; } ub;
#pragma unroll
    for (int jj = 0; jj < 4; ++jj) ub.u[jj] = pack2(h[2 * jj], h[2 * jj + 1]);
    float4v z4 = {0.f, 0.f, 0.f, 0.f};
    float4v d0 = __builtin_amdgcn_mfma_f32_16x16x32_bf16(a0v, ub.v, z4, 0, 0, 0);
    float4v d1 = __builtin_amdgcn_mfma_f32_16x16x32_bf16(a1v, ub.v, z4, 0, 0, 0);
    outs[p][0] = packh(d0[0] * dv, d0[1] * dv);
    outs[p][1] = packh(d0[2] * dv, d0[3] * dv);
    outs[p][2] = packh(d1[0] * dv, d1[1] * dv);
    outs[p][3] = packh(d1[2] * dv, d1[3] * dv);
  }
  __syncthreads();
#pragma unroll
  for (int p = 0; p < 3; ++p) {
    const int node = nodes[p];
    if (node >= 0) {
      const int sw = (node >> 1) & 3;
      u32* op = sy + node * 16;
      uint2 s0 = { outs[p][0], outs[p][1] };
      uint2 s1 = { outs[p][2], outs[p][3] };
      *(uint2*)(op + (((kg >> 1) ^ sw) << 2) + ((2 * kg) & 3)) = s0;
      *(uint2*)(op + (((2 + (kg >> 1)) ^ sw) << 2) + ((2 * kg) & 3)) = s1;
    }
  }
  __syncthreads();
}

__global__ __launch_bounds__(1024) void k_fused(
    const u32* __restrict__ yin, const float* __restrict__ dinv,
    const u16* __restrict__ perm_g, const u16* __restrict__ ell_g,
    const u16* __restrict__ elloff_g,
    const float* __restrict__ b1, const float* __restrict__ W2,
    const float* __restrict__ b2, const float* __restrict__ W3,
    const float* __restrict__ b3, const float* __restrict__ W4,
    const float* __restrict__ b4, const float* __restrict__ Wf1,
    const float* __restrict__ bf1, const float* __restrict__ Wf2,
    const float* __restrict__ bf2, float* __restrict__ out)
{
  const int b = blockIdx.x;
  const int tid = threadIdx.x;
  const int lane = tid & 63;
  const int wv = tid >> 6;          // wave 0..15
  const int col = lane & 15;
  const int kg = lane >> 4;

  __shared__ __align__(16) char smem[65408];
  u32*   s_y      = (u32*)smem;                     // 45760 B (715 rows; dead later)
  u16*   s_ell    = (u16*)(smem + 45760);           // 13824
  u16*   s_elloff = (u16*)(smem + 59584);           // 96
  float* s_dv     = (float*)(smem + 59680);         // 2864 (incl dummy)
  float* s_h      = (float*)(smem + 62544);         // 2864 (incl dummy)
  float* s_red    = (float*)smem;                   // aliases dead s_y
  float* s_u      = (float*)(smem + 8192);          // aliases dead s_y

  {
    const uint4* __restrict__ ysrc = (const uint4*)(yin + (size_t)b * NN * 16);
    uint4* sy4w = (uint4*)s_y;
    const uint4 z4 = {0, 0, 0, 0};
    for (int s = tid; s < (NN + 1) * 4; s += 1024) {
      const int node = s >> 2;
      sy4w[yslot(node, s & 3)] = (node < NN) ? ysrc[s] : z4;
    }
    const uint4* __restrict__ esrc = (const uint4*)(ell_g + (size_t)b * ELLB);
    uint4* ed = (uint4*)s_ell;
    for (int s = tid; s < ELLB / 8; s += 1024) ed[s] = esrc[s];
    for (int i = tid; i <= NT16; i += 1024) s_elloff[i] = elloff_g[(size_t)b * (NT16 + 1) + i];
    for (int i = tid; i < NN; i += 1024) s_dv[i] = dinv[(size_t)b * NN + i];
    if (tid == 1023) s_dv[NN] = 0.f;
  }
  u16 pvs[3];
#pragma unroll
  for (int p = 0; p < 3; ++p) {
    const int t = p * 16 + wv;
    pvs[p] = (t < NT16) ? perm_g[(size_t)b * NPAD + t * 16 + col] : (u16)0xFFFF;
  }
  const u16 pvt = (tid < NPAD) ? perm_g[(size_t)b * NPAD + tid] : (u16)0xFFFF;

  union { u32 u[4]; short8 v; } uaA0, uaA1, uaB0, uaB1;
#pragma unroll
  for (int jj = 0; jj < 4; ++jj) {
    uaA0.u[jj] = pack2(W2[(kg * 8 + 2 * jj) * CH + col],      W2[(kg * 8 + 2 * jj + 1) * CH + col]);
    uaA1.u[jj] = pack2(W2[(kg * 8 + 2 * jj) * CH + 16 + col], W2[(kg * 8 + 2 * jj + 1) * CH + 16 + col]);
    uaB0.u[jj] = pack2(W3[(kg * 8 + 2 * jj) * CH + col],      W3[(kg * 8 + 2 * jj + 1) * CH + col]);
    uaB1.u[jj] = pack2(W3[(kg * 8 + 2 * jj) * CH + 16 + col], W3[(kg * 8 + 2 * jj + 1) * CH + 16 + col]);
  }
  float b1r[8], b2r[8], b3r[8], w4r[8];
#pragma unroll
  for (int j = 0; j < 8; ++j) {
    b1r[j] = b1[kg * 8 + j];
    b2r[j] = b2[kg * 8 + j];
    b3r[j] = b3[kg * 8 + j];
    w4r[j] = W4[kg * 8 + j];
  }
  const float bb4 = b4[0];
  __syncthreads();

  gcn_pass32<0>(s_y, s_ell, s_elloff, s_dv, pvs, wv, col, kg, uaA0.v, uaA1.v, b1r);
  gcn_pass32<1>(s_y, s_ell, s_elloff, s_dv, pvs, wv, col, kg, uaB0.v, uaB1.v, b2r);

  // layer 4: agg + b3, lrelu+t, dot W4 (32->1), *dinv -> s_h
  {
    const uint4* sy4 = (const uint4*)s_y;
    const f16x2 hz = {(_Float16)0, (_Float16)0};
#pragma unroll
    for (int p = 0; p < 3; ++p) {
      const int t = p * 16 + wv;
      const int pv = (t < NT16) ? (int)pvs[p] : 0xFFFF;
      const int node = (pv == 0xFFFF) ? NN : pv;
      int base = 0, md4 = 0;
      if (t < NT16) { base = s_elloff[t]; md4 = s_elloff[t + 1] - base; }
      base = __builtin_amdgcn_readfirstlane(base);
      md4 = __builtin_amdgcn_readfirstlane(md4);
      f16x2 a0h, a1h, a2h, a3h;
      {
        uint4 u = sy4[yslot(node, kg)];
        a0h = u2h(u.x); a1h = u2h(u.y); a2h = u2h(u.z); a3h = u2h(u.w);
      }
      float zx[8];
#pragma unroll
      for (int j = 0; j < 8; ++j) zx[j] = 0.f;
      const u16* ep = s_ell + base * 16 + col;
      AGG_LOOP(ep)
      const float dv = s_dv[node];
      float part = 0.f;
#pragma unroll
      for (int j = 0; j < 8; ++j) {
        float t2 = fmaf(dv, zx[j], b3r[j]);
        float l = (t2 > 0.f) ? t2 : 0.01f * t2;
        part = fmaf(l + t2, w4r[j], part);
      }
      part += __shfl_xor(part, 16, 64);
      part += __shfl_xor(part, 32, 64);
      if (pv != 0xFFFF && kg == 0) s_h[node] = part * dv;
    }
  }
  __syncthreads();
  if (tid == 1023) s_h[NN] = 0.f;
  __syncthreads();

  // tail aggregation via ELL: z = h[node] + sum h[e0>>2]; lrelu(dinv*z + b4)
  {
    float hval = 0.f;
    int node = -1;
    if (tid < NPAD && pvt != 0xFFFF) {
      node = (int)pvt;
      const int t = tid >> 4, c = tid & 15;
      const int base = s_elloff[t], md4 = s_elloff[t + 1] - base;
      float z = s_h[node];
      const u16* ep = s_ell + base * 16 + c;
      for (int kk = 0; kk < md4; ++kk) z += s_h[((int)ep[kk * 16]) >> 2];
      float t2 = fmaf(s_dv[node], z, bb4);
      hval = (t2 > 0.f) ? t2 : 0.01f * t2;
    }
    __syncthreads();
    if (node >= 0) s_h[node] = hval;
  }
  __syncthreads();

  // FC1: 714 -> 128, 8-way split-K
  const int j = tid & 127, q = tid >> 7;
  {
    const int n0 = (q * NN) >> 3, n1 = ((q + 1) * NN) >> 3;
    const float* __restrict__ w = Wf1 + j;
    float a0 = 0.f, a1 = 0.f;
    int n = n0;
#pragma unroll 4
    for (; n + 2 <= n1; n += 2) {
      a0 = fmaf(s_h[n], w[(size_t)n * 128], a0);
      a1 = fmaf(s_h[n + 1], w[(size_t)(n + 1) * 128], a1);
    }
    if (n < n1) a0 = fmaf(s_h[n], w[(size_t)n * 128], a0);
    s_red[tid] = a0 + a1;
  }
  __syncthreads();
  if (tid < 128) {
    float v = bf1[tid];
#pragma unroll
    for (int m = 0; m < 8; ++m) v += s_red[tid + 128 * m];
    s_u[tid] = fmaxf(v, 0.f);
  }
  __syncthreads();
  // FC2: 128 -> 128, 8-way split-K
  {
    const float* __restrict__ w = Wf2 + j;
    float a0 = 0.f, a1 = 0.f;
#pragma unroll
    for (int k = q * 16; k < q * 16 + 16; k += 2) {
      a0 = fmaf(s_u[k], w[(size_t)k * 128], a0);
      a1 = fmaf(s_u[k + 1], w[(size_t)(k + 1) * 128], a1);
    }
    s_red[tid] = a0 + a1;
  }
  __syncthreads();
  if (tid < 128) {
    float v = bf2[tid];
#pragma unroll
    for (int m = 0; m < 8; ++m) v += s_red[tid + 128 * m];
    out[(size_t)b * 128 + tid] = fmaxf(v, 0.f);
  }
}

extern "C" void kernel_launch(void* const* d_in, const int* in_sizes, int n_in,
                              void* d_out, int out_size, void* d_ws, size_t ws_size,
                              hipStream_t stream)
{
  (void)in_sizes; (void)n_in; (void)out_size; (void)ws_size;
  const int*   ids  = (const int*)d_in[0];
  const float* cont = (const float*)d_in[1];
  const int*   edges= (const int*)d_in[2];
  const float* emb  = (const float*)d_in[3];
  const float* W1   = (const float*)d_in[4];
  const float* b1   = (const float*)d_in[5];
  const float* W2   = (const float*)d_in[6];
  const float* b2   = (const float*)d_in[7];
  const float* W3   = (const float*)d_in[8];
  const float* b3   = (const float*)d_in[9];
  const float* W4   = (const float*)d_in[10];
  const float* b4   = (const float*)d_in[11];
  const float* Wf1  = (const float*)d_in[12];
  const float* bf1  = (const float*)d_in[13];
  const float* Wf2  = (const float*)d_in[14];
  const float* bf2  = (const float*)d_in[15];
  float* out = (float*)d_out;

  char* ws = (char*)d_ws;
  size_t off = 0;
  auto alloc = [&](size_t bytes) -> void* {
    void* p = ws + off;
    off = (off + bytes + 255) & ~(size_t)255;
    return p;
  };
  float* dinv     = (float*)alloc((size_t)BB * NN * 4);
  u16*   perm     = (u16*)  alloc((size_t)BB * NPAD * 2);
  u16*   ell      = (u16*)  alloc((size_t)BB * ELLB * 2);
  u16*   elloff   = (u16*)  alloc((size_t)BB * (NT16 + 1) * 2);
  uint2* embh     = (uint2*)alloc((size_t)VOCAB * 64 * 2);
  u32*   yA       = (u32*)  alloc((size_t)BB * NN * 16 * 4);

  hipLaunchKernelGGL(k_setup, dim3(NCONV + BB), dim3(256), 0, stream,
                     emb, embh, edges, dinv, perm, ell, elloff);
  hipLaunchKernelGGL(k_gcn1m, dim3(BB * 6), dim3(256), 0, stream,
                     ids, cont, (const uint4*)embh, W1, dinv, yA);
  hipLaunchKernelGGL(k_fused, dim3(BB), dim3(1024), 0, stream,
                     yA, dinv, perm, ell, elloff,
                     b1, W2, b2, W3, b3, W4, b4, Wf1, bf1, Wf2, bf2, out);
}

// Round 18
// 102.640 us; speedup vs baseline: 1.1377x; 1.0750x over previous
//
#include <hip/hip_runtime.h>
#include <hip/hip_bf16.h>

#define BB 512
#define NN 714
#define EE 4096
#define ED2 62
#define CH 32
#define NT16 45    // ceil(NN/16)
#define NPAD 720   // NT16*16
#define VOCAB 38733
#define NCONV 2421 // ceil(VOCAB*16/256)
#define ELLR 432   // ELL row capacity (rows of 16 u16), rows per tile padded to x4
#define ELLB (ELLR*16)

typedef unsigned int u32;
typedef unsigned short u16;
typedef short short8 __attribute__((ext_vector_type(8)));
typedef float float4v __attribute__((ext_vector_type(4)));
typedef _Float16 f16x2 __attribute__((ext_vector_type(2)));
typedef __fp16 fp16x2 __attribute__((ext_vector_type(2)));

__device__ __forceinline__ u32 f2bf(float f) {
  u32 u = __float_as_uint(f);
  return (u + 0x7fffu + ((u >> 16) & 1u)) >> 16;
}
__device__ __forceinline__ u32 pack2(float a, float b) {
  return f2bf(a) | (f2bf(b) << 16);
}
__device__ __forceinline__ f16x2 u2h(u32 x) { union { u32 u; f16x2 h; } c; c.u = x; return c.h; }
__device__ __forceinline__ u32 packh(float a, float b) {
  union { fp16x2 h; u32 u; } c;
  c.h = __builtin_amdgcn_cvt_pkrtz(a, b);
  return c.u;
}

// y-in-LDS swizzle: uint4 slot q of node -> q ^ ((node>>1)&3).
// Note: yslot(r, kg) == yslot(r, 0) ^ kg  (kg<4 stays within the low 2 bits).
__device__ __forceinline__ int yslot(int node, int q) {
  return (node << 2) | (q ^ ((node >> 1) & 3));
}

// ---------------- Fused setup kernel: emb->bf16 table (blocks < NCONV) + per-batch prep ----------------
__global__ __launch_bounds__(256) void k_setup(const float* __restrict__ emb,
    uint2* __restrict__ embh, const int* __restrict__ edges,
    float* __restrict__ dinv, u16* __restrict__ perm_g,
    u16* __restrict__ ell_g, u16* __restrict__ elloff_g)
{
  const int tid = threadIdx.x;
  if (blockIdx.x < NCONV) {
    const int t = blockIdx.x * 256 + tid;
    if (t < VOCAB * 16) {
      const int row = t >> 4, c = (t & 15) * 4;
      const float* __restrict__ p = emb + (size_t)row * ED2;
      float v0 = (c + 0 < ED2) ? p[c + 0] : 0.f;
      float v1 = (c + 1 < ED2) ? p[c + 1] : 0.f;
      float v2 = (c + 2 < ED2) ? p[c + 2] : 0.f;
      float v3 = (c + 3 < ED2) ? p[c + 3] : 0.f;
      uint2 o = { pack2(v0, v1), pack2(v2, v3) };
      embh[t] = o;
    }
    return;
  }
  const int b = blockIdx.x - NCONV;
  const int* __restrict__ er = edges + (size_t)b * 2 * EE;       // e[0] = source (row)
  const int* __restrict__ ec = er + EE;                          // e[1] = target (col)
  __shared__ int s_cnt[NN];
  __shared__ int s_a[1024];
  __shared__ int s_b[1024];
  __shared__ u16 s_rows16[EE];
  __shared__ u16 s_perm[NPAD];
  __shared__ u16 s_degP[NPAD];
  __shared__ int s_hist[64];
  __shared__ int s_md[NT16 + 1];

  for (int i = tid; i < NN; i += 256) s_cnt[i] = 0;
  __syncthreads();
  for (int e = tid; e < EE; e += 256) atomicAdd(&s_cnt[ec[e]], 1);
  __syncthreads();
  for (int i = tid; i < 1024; i += 256) s_a[i] = (i < NN) ? s_cnt[i] : 0;
  for (int i = tid; i < NN; i += 256)
    dinv[(size_t)b * NN + i] = rsqrtf((float)(s_cnt[i] + 1));    // +1 self loop
  __syncthreads();
  int* src = s_a; int* dst = s_b;
  for (int d = 1; d < 1024; d <<= 1) {
    for (int i = tid; i < 1024; i += 256) {
      int v = src[i];
      if (i >= d) v += src[i - d];
      dst[i] = v;
    }
    __syncthreads();
    int* t = src; src = dst; dst = t;
  }
  // src (= s_a, 10 swaps) = inclusive scan of degree counts
  for (int i = tid; i < NN; i += 256) s_cnt[i] = 0;  // fill cursors
  __syncthreads();
  for (int e = tid; e < EE; e += 256) {
    int c = ec[e];
    int p = atomicAdd(&s_cnt[c], 1);
    int base = (c == 0) ? 0 : src[c - 1];
    s_rows16[base + p] = (u16)er[e];
  }
  // degree-sorted perm (counting sort, 64 bins)
  for (int i = tid; i < 64; i += 256) s_hist[i] = 0;
  for (int i = tid; i < NPAD; i += 256) { s_perm[i] = 0xFFFFu; s_degP[i] = 0; }
  __syncthreads();
  for (int i = tid; i < NN; i += 256) {
    int deg = src[i] - (i ? src[i - 1] : 0);
    atomicAdd(&s_hist[deg < 63 ? deg : 63], 1);
  }
  __syncthreads();
  // wave-parallel exclusive scan of the 64 histogram bins
  if (tid < 64) {
    int v = s_hist[tid];
    int incl = v;
#pragma unroll
    for (int d = 1; d < 64; d <<= 1) {
      int o = __shfl_up(incl, d, 64);
      if (tid >= d) incl += o;
    }
    s_hist[tid] = incl - v;
  }
  __syncthreads();
  for (int i = tid; i < NN; i += 256) {
    int deg = src[i] - (i ? src[i - 1] : 0);
    int pos = atomicAdd(&s_hist[deg < 63 ? deg : 63], 1);
    s_perm[pos] = (u16)i;
    s_degP[pos] = (u16)deg;
  }
  __syncthreads();
  for (int i = tid; i < NPAD; i += 256) perm_g[(size_t)b * NPAD + i] = s_perm[i];
  // per-tile max degree, padded to multiple of 4
  if (tid < NT16) {
    int md = 0;
#pragma unroll
    for (int c = 0; c < 16; ++c) { int d = s_degP[tid * 16 + c]; md = d > md ? d : md; }
    s_md[tid] = (md + 3) & ~3;
  }
  __syncthreads();
  // wave-parallel exclusive scan of the 45 tile sizes (clamped to ELLR)
  if (tid < 64) {
    int m = (tid < NT16) ? s_md[tid] : 0;
    int incl = m;
#pragma unroll
    for (int d = 1; d < 64; d <<= 1) {
      int o = __shfl_up(incl, d, 64);
      if (tid >= d) incl += o;
    }
    int excl = incl - m;
    if (excl > ELLR) excl = ELLR;
    if (tid < NT16) s_md[tid] = excl;
    if (tid == NT16 - 1) s_md[NT16] = (incl > ELLR) ? ELLR : incl;
  }
  __syncthreads();
  if (tid <= NT16) elloff_g[(size_t)b * (NT16 + 1) + tid] = (u16)s_md[tid];
  // fill ELL per-wave (wave w takes tiles w, w+4, ...), PRE-SWIZZLED entries (pad -> dummy NN)
  {
    const int wv4 = tid >> 6, lane = tid & 63;
    u16* eg = ell_g + (size_t)b * ELLB;
    for (int t = wv4; t < NT16; t += 4) {
      const int base = s_md[t], md4 = s_md[t + 1] - base;
      for (int s = lane; s < md4 * 16; s += 64) {
        const int kk = s >> 4, col = s & 15;
        const int pv = s_perm[t * 16 + col];
        int r = NN;
        if (pv != 0xFFFF) {
          const int deg = s_degP[t * 16 + col];
          if (kk < deg) {
            const int off = pv ? src[pv - 1] : 0;
            r = (int)s_rows16[off + kk];
          }
        }
        eg[base * 16 + s] = (u16)((r << 2) | ((r >> 1) & 3));
      }
    }
  }
}

// ---------------- Kernel B: MFMA GCN1, 128-node chunks, 256 threads, fp16 y1 out ----------------
__global__ __launch_bounds__(256) void k_gcn1m(
    const int* __restrict__ ids, const float* __restrict__ cont,
    const uint4* __restrict__ embh, const float* __restrict__ W1,
    const float* __restrict__ dinv, u32* __restrict__ y1)
{
  const int bid = blockIdx.x;
  const int b = bid / 6, blk = bid - b * 6;
  const int base = blk * 128;
  const int nnodes = (NN - base < 128) ? (NN - base) : 128;
  const int nrows = nnodes * 2;
  const int tid = threadIdx.x, lane = tid & 63, wv = tid >> 6;
  const int col = lane & 15, kg = lane >> 4;

  __shared__ __align__(16) unsigned short sX[128 * 128];
  __shared__ float sC[128][4];
  __shared__ int s_ids[256];

  for (int t = tid; t < nnodes * 3; t += 256)
    sC[t / 3][t % 3] = cont[((size_t)b * NN + base) * 3 + t];
  s_ids[tid] = (tid < nrows) ? ids[((size_t)b * NN + base) * 2 + tid] : -1;
  __syncthreads();

  const int ck = tid & 7;
  const int rbase = tid >> 3;
  {
    uint4 w4[8];
#pragma unroll
    for (int q = 0; q < 8; ++q) {
      const int id = s_ids[q * 32 + rbase];
      if (id >= 0) w4[q] = embh[(size_t)id * 8 + ck];
      else { w4[q].x = 0; w4[q].y = 0; w4[q].z = 0; w4[q].w = 0; }
    }
#pragma unroll
    for (int q = 0; q < 8; ++q) {
      const int r = q * 32 + rbase;
      const int node = r >> 1, slot = r & 1;
      const int c16 = (node * 16 + slot * 8 + ck) ^ (node & 7);
      ((uint4*)sX)[c16] = w4[q];
    }
  }

  union { u32 u[4]; short8 v; } A[4][2];
#pragma unroll
  for (int kc = 0; kc < 4; ++kc)
#pragma unroll
    for (int hh = 0; hh < 2; ++hh)
#pragma unroll
      for (int jj = 0; jj < 4; ++jj) {
        const int k0 = kc * 32 + kg * 8 + 2 * jj;
        const int k1 = k0 + 1;
        const int m0 = (k0 < 62) ? k0 : ((k0 >= 64 && k0 < 126) ? k0 - 2 : -1);
        const int m1 = (k1 < 62) ? k1 : ((k1 >= 64 && k1 < 126) ? k1 - 2 : -1);
        const float wa = (m0 >= 0) ? W1[m0 * CH + hh * 16 + col] : 0.f;
        const float wb = (m1 >= 0) ? W1[m1 * CH + hh * 16 + col] : 0.f;
        A[kc][hh].u[jj] = pack2(wa, wb);
      }
  float Wc0[3][4], Wc1[3][4];
#pragma unroll
  for (int j = 0; j < 3; ++j)
#pragma unroll
    for (int reg = 0; reg < 4; ++reg) {
      Wc0[j][reg] = W1[(124 + j) * CH + 4 * kg + reg];
      Wc1[j][reg] = W1[(124 + j) * CH + 16 + 4 * kg + reg];
    }
  __syncthreads();

  const int ntiles = (nnodes + 15) >> 4;
  for (int t = wv; t < ntiles; t += 4) {
    const int ln = t * 16 + col;
    float4v a0 = {0.f, 0.f, 0.f, 0.f}, a1 = {0.f, 0.f, 0.f, 0.f};
#pragma unroll
    for (int kc = 0; kc < 4; ++kc) {
      const int idx16 = (ln * 16 + kc * 4 + kg) ^ (ln & 7);
      short8 bf = *(const short8*)(sX + idx16 * 8);
      a0 = __builtin_amdgcn_mfma_f32_16x16x32_bf16(A[kc][0].v, bf, a0, 0, 0, 0);
      a1 = __builtin_amdgcn_mfma_f32_16x16x32_bf16(A[kc][1].v, bf, a1, 0, 0, 0);
    }
#pragma unroll
    for (int j = 0; j < 3; ++j) {
      const float cv = sC[ln][j];
#pragma unroll
      for (int reg = 0; reg < 4; ++reg) {
        a0[reg] = fmaf(cv, Wc0[j][reg], a0[reg]);
        a1[reg] = fmaf(cv, Wc1[j][reg], a1[reg]);
      }
    }
    if (ln < nnodes) {
      const int gnode = base + ln;
      const float dv = dinv[(size_t)b * NN + gnode];
      u32* op = y1 + ((size_t)b * NN + gnode) * 16;
      uint2 s0 = { packh(a0[0] * dv, a0[1] * dv), packh(a0[2] * dv, a0[3] * dv) };
      uint2 s1 = { packh(a1[0] * dv, a1[1] * dv), packh(a1[2] * dv, a1[3] * dv) };
      *(uint2*)(op + 2 * kg) = s0;
      *(uint2*)(op + 8 + 2 * kg) = s1;
    }
  }
}

// ---------------- Fused kernel: layers 2,3,4 + tail ----------------
// y in LDS is fp16; aggregation via v_pk_add_f16 with DUAL accumulator sets
// (even/odd edges -> a*/b*, merged at f32 flush every 16 edges) to halve the
// serial pk_add dependency chain. ELL entries pre-swizzled: a16 = e0 ^ kg.
#define EDGEA(EP, K) { const int a16 = ((int)(EP)[(K) * 16]) ^ kg; \
  uint4 n = sy4[a16]; \
  a0h += u2h(n.x); a1h += u2h(n.y); a2h += u2h(n.z); a3h += u2h(n.w); }
#define EDGEB(EP, K) { const int a16 = ((int)(EP)[(K) * 16]) ^ kg; \
  uint4 n = sy4[a16]; \
  b0h += u2h(n.x); b1h += u2h(n.y); b2h += u2h(n.z); b3h += u2h(n.w); }
#define FLUSH { a0h += b0h; a1h += b1h; a2h += b2h; a3h += b3h; \
  zx[0] += (float)a0h.x; zx[1] += (float)a0h.y; \
  zx[2] += (float)a1h.x; zx[3] += (float)a1h.y; \
  zx[4] += (float)a2h.x; zx[5] += (float)a2h.y; \
  zx[6] += (float)a3h.x; zx[7] += (float)a3h.y; \
  a0h = hz; a1h = hz; a2h = hz; a3h = hz; \
  b0h = hz; b1h = hz; b2h = hz; b3h = hz; }
#define AGG_LOOP(EP) { int kk = 0; \
  while (kk + 16 <= md4) { \
    _Pragma("unroll") for (int e = 0; e < 16; e += 2) { EDGEA(EP, kk + e) EDGEB(EP, kk + e + 1) } \
    FLUSH \
    kk += 16; } \
  if (kk + 8 <= md4) { \
    _Pragma("unroll") for (int e = 0; e < 8; e += 2) { EDGEA(EP, kk + e) EDGEB(EP, kk + e + 1) } \
    FLUSH \
    kk += 8; } \
  if (kk < md4) { \
    _Pragma("unroll") for (int e = 0; e < 4; e += 2) { EDGEA(EP, kk + e) EDGEB(EP, kk + e + 1) } \
    FLUSH } }

template<int ACT>
__device__ __forceinline__ void gcn_pass32(
    u32* __restrict__ sy, const u16* __restrict__ s_ell,
    const u16* __restrict__ s_elloff, const float* __restrict__ s_dv,
    const u16* __restrict__ pvs,
    const int wv, const int col, const int kg,
    const short8 a0v, const short8 a1v, const float* __restrict__ bias8)
{
  const uint4* sy4 = (const uint4*)sy;
  const f16x2 hz = {(_Float16)0, (_Float16)0};
  u32 outs[3][4];
  int nodes[3];
#pragma unroll
  for (int p = 0; p < 3; ++p) {
    const int t = p * 16 + wv;
    const int pv = (t < NT16) ? (int)pvs[p] : 0xFFFF;
    const int node = (pv == 0xFFFF) ? NN : pv;
    nodes[p] = (pv == 0xFFFF) ? -1 : pv;
    int base = 0, md4 = 0;
    if (t < NT16) { base = s_elloff[t]; md4 = s_elloff[t + 1] - base; }
    base = __builtin_amdgcn_readfirstlane(base);
    md4 = __builtin_amdgcn_readfirstlane(md4);
    f16x2 a0h, a1h, a2h, a3h;
    f16x2 b0h = hz, b1h = hz, b2h = hz, b3h = hz;
    {
      uint4 u = sy4[yslot(node, kg)];          // self (dummy row = zeros)
      a0h = u2h(u.x); a1h = u2h(u.y); a2h = u2h(u.z); a3h = u2h(u.w);
    }
    float zx[8];
#pragma unroll
    for (int j = 0; j < 8; ++j) zx[j] = 0.f;
    const u16* ep = s_ell + base * 16 + col;
    AGG_LOOP(ep)
    const float dv = s_dv[node];               // dummy dv = 0
    float h[8];
#pragma unroll
    for (int j = 0; j < 8; ++j) {
      float t2 = fmaf(dv, zx[j], bias8[j]);
      float l = (t2 > 0.f) ? t2 : 0.01f * t2;
      h[j] = (ACT == 0) ? l : (l + t2);
    }
    union { u32 u[4]; short8 v; } ub;
#pragma unroll
    for (int jj = 0; jj < 4; ++jj) ub.u[jj] = pack2(h[2 * jj], h[2 * jj + 1]);
    float4v z4 = {0.f, 0.f, 0.f, 0.f};
    float4v d0 = __builtin_amdgcn_mfma_f32_16x16x32_bf16(a0v, ub.v, z4, 0, 0, 0);
    float4v d1 = __builtin_amdgcn_mfma_f32_16x16x32_bf16(a1v, ub.v, z4, 0, 0, 0);
    outs[p][0] = packh(d0[0] * dv, d0[1] * dv);
    outs[p][1] = packh(d0[2] * dv, d0[3] * dv);
    outs[p][2] = packh(d1[0] * dv, d1[1] * dv);
    outs[p][3] = packh(d1[2] * dv, d1[3] * dv);
  }
  __syncthreads();
#pragma unroll
  for (int p = 0; p < 3; ++p) {
    const int node = nodes[p];
    if (node >= 0) {
      const int sw = (node >> 1) & 3;
      u32* op = sy + node * 16;
      uint2 s0 = { outs[p][0], outs[p][1] };
      uint2 s1 = { outs[p][2], outs[p][3] };
      *(uint2*)(op + (((kg >> 1) ^ sw) << 2) + ((2 * kg) & 3)) = s0;
      *(uint2*)(op + (((2 + (kg >> 1)) ^ sw) << 2) + ((2 * kg) & 3)) = s1;
    }
  }
  __syncthreads();
}

__global__ __launch_bounds__(1024) void k_fused(
    const u32* __restrict__ yin, const float* __restrict__ dinv,
    const u16* __restrict__ perm_g, const u16* __restrict__ ell_g,
    const u16* __restrict__ elloff_g,
    const float* __restrict__ b1, const float* __restrict__ W2,
    const float* __restrict__ b2, const float* __restrict__ W3,
    const float* __restrict__ b3, const float* __restrict__ W4,
    const float* __restrict__ b4, const float* __restrict__ Wf1,
    const float* __restrict__ bf1, const float* __restrict__ Wf2,
    const float* __restrict__ bf2, float* __restrict__ out)
{
  const int b = blockIdx.x;
  const int tid = threadIdx.x;
  const int lane = tid & 63;
  const int wv = tid >> 6;          // wave 0..15
  const int col = lane & 15;
  const int kg = lane >> 4;

  __shared__ __align__(16) char smem[65408];
  u32*   s_y      = (u32*)smem;                     // 45760 B (715 rows; dead later)
  u16*   s_ell    = (u16*)(smem + 45760);           // 13824
  u16*   s_elloff = (u16*)(smem + 59584);           // 96
  float* s_dv     = (float*)(smem + 59680);         // 2864 (incl dummy)
  float* s_h      = (float*)(smem + 62544);         // 2864 (incl dummy)
  float* s_red    = (float*)smem;                   // aliases dead s_y
  float* s_u      = (float*)(smem + 8192);          // aliases dead s_y

  {
    const uint4* __restrict__ ysrc = (const uint4*)(yin + (size_t)b * NN * 16);
    uint4* sy4w = (uint4*)s_y;
    const uint4 z4 = {0, 0, 0, 0};
    for (int s = tid; s < (NN + 1) * 4; s += 1024) {
      const int node = s >> 2;
      sy4w[yslot(node, s & 3)] = (node < NN) ? ysrc[s] : z4;
    }
    const uint4* __restrict__ esrc = (const uint4*)(ell_g + (size_t)b * ELLB);
    uint4* ed = (uint4*)s_ell;
    for (int s = tid; s < ELLB / 8; s += 1024) ed[s] = esrc[s];
    for (int i = tid; i <= NT16; i += 1024) s_elloff[i] = elloff_g[(size_t)b * (NT16 + 1) + i];
    for (int i = tid; i < NN; i += 1024) s_dv[i] = dinv[(size_t)b * NN + i];
    if (tid == 1023) s_dv[NN] = 0.f;
  }
  u16 pvs[3];
#pragma unroll
  for (int p = 0; p < 3; ++p) {
    const int t = p * 16 + wv;
    pvs[p] = (t < NT16) ? perm_g[(size_t)b * NPAD + t * 16 + col] : (u16)0xFFFF;
  }
  const u16 pvt = (tid < NPAD) ? perm_g[(size_t)b * NPAD + tid] : (u16)0xFFFF;

  union { u32 u[4]; short8 v; } uaA0, uaA1, uaB0, uaB1;
#pragma unroll
  for (int jj = 0; jj < 4; ++jj) {
    uaA0.u[jj] = pack2(W2[(kg * 8 + 2 * jj) * CH + col],      W2[(kg * 8 + 2 * jj + 1) * CH + col]);
    uaA1.u[jj] = pack2(W2[(kg * 8 + 2 * jj) * CH + 16 + col], W2[(kg * 8 + 2 * jj + 1) * CH + 16 + col]);
    uaB0.u[jj] = pack2(W3[(kg * 8 + 2 * jj) * CH + col],      W3[(kg * 8 + 2 * jj + 1) * CH + col]);
    uaB1.u[jj] = pack2(W3[(kg * 8 + 2 * jj) * CH + 16 + col], W3[(kg * 8 + 2 * jj + 1) * CH + 16 + col]);
  }
  float b1r[8], b2r[8], b3r[8], w4r[8];
#pragma unroll
  for (int j = 0; j < 8; ++j) {
    b1r[j] = b1[kg * 8 + j];
    b2r[j] = b2[kg * 8 + j];
    b3r[j] = b3[kg * 8 + j];
    w4r[j] = W4[kg * 8 + j];
  }
  const float bb4 = b4[0];
  __syncthreads();

  gcn_pass32<0>(s_y, s_ell, s_elloff, s_dv, pvs, wv, col, kg, uaA0.v, uaA1.v, b1r);
  gcn_pass32<1>(s_y, s_ell, s_elloff, s_dv, pvs, wv, col, kg, uaB0.v, uaB1.v, b2r);

  // layer 4: agg + b3, lrelu+t, dot W4 (32->1), *dinv -> s_h
  {
    const uint4* sy4 = (const uint4*)s_y;
    const f16x2 hz = {(_Float16)0, (_Float16)0};
#pragma unroll
    for (int p = 0; p < 3; ++p) {
      const int t = p * 16 + wv;
      const int pv = (t < NT16) ? (int)pvs[p] : 0xFFFF;
      const int node = (pv == 0xFFFF) ? NN : pv;
      int base = 0, md4 = 0;
      if (t < NT16) { base = s_elloff[t]; md4 = s_elloff[t + 1] - base; }
      base = __builtin_amdgcn_readfirstlane(base);
      md4 = __builtin_amdgcn_readfirstlane(md4);
      f16x2 a0h, a1h, a2h, a3h;
      f16x2 b0h = hz, b1h = hz, b2h = hz, b3h = hz;
      {
        uint4 u = sy4[yslot(node, kg)];
        a0h = u2h(u.x); a1h = u2h(u.y); a2h = u2h(u.z); a3h = u2h(u.w);
      }
      float zx[8];
#pragma unroll
      for (int j = 0; j < 8; ++j) zx[j] = 0.f;
      const u16* ep = s_ell + base * 16 + col;
      AGG_LOOP(ep)
      const float dv = s_dv[node];
      float part = 0.f;
#pragma unroll
      for (int j = 0; j < 8; ++j) {
        float t2 = fmaf(dv, zx[j], b3r[j]);
        float l = (t2 > 0.f) ? t2 : 0.01f * t2;
        part = fmaf(l + t2, w4r[j], part);
      }
      part += __shfl_xor(part, 16, 64);
      part += __shfl_xor(part, 32, 64);
      if (pv != 0xFFFF && kg == 0) s_h[node] = part * dv;
    }
  }
  __syncthreads();
  if (tid == 1023) s_h[NN] = 0.f;
  __syncthreads();

  // tail aggregation via ELL: z = h[node] + sum h[e0>>2]; lrelu(dinv*z + b4)
  {
    float hval = 0.f;
    int node = -1;
    if (tid < NPAD && pvt != 0xFFFF) {
      node = (int)pvt;
      const int t = tid >> 4, c = tid & 15;
      const int base = s_elloff[t], md4 = s_elloff[t + 1] - base;
      float z = s_h[node];
      const u16* ep = s_ell + base * 16 + c;
      for (int kk = 0; kk < md4; ++kk) z += s_h[((int)ep[kk * 16]) >> 2];
      float t2 = fmaf(s_dv[node], z, bb4);
      hval = (t2 > 0.f) ? t2 : 0.01f * t2;
    }
    __syncthreads();
    if (node >= 0) s_h[node] = hval;
  }
  __syncthreads();

  // FC1: 714 -> 128, 8-way split-K
  const int j = tid & 127, q = tid >> 7;
  {
    const int n0 = (q * NN) >> 3, n1 = ((q + 1) * NN) >> 3;
    const float* __restrict__ w = Wf1 + j;
    float a0 = 0.f, a1 = 0.f;
    int n = n0;
#pragma unroll 4
    for (; n + 2 <= n1; n += 2) {
      a0 = fmaf(s_h[n], w[(size_t)n * 128], a0);
      a1 = fmaf(s_h[n + 1], w[(size_t)(n + 1) * 128], a1);
    }
    if (n < n1) a0 = fmaf(s_h[n], w[(size_t)n * 128], a0);
    s_red[tid] = a0 + a1;
  }
  __syncthreads();
  if (tid < 128) {
    float v = bf1[tid];
#pragma unroll
    for (int m = 0; m < 8; ++m) v += s_red[tid + 128 * m];
    s_u[tid] = fmaxf(v, 0.f);
  }
  __syncthreads();
  // FC2: 128 -> 128, 8-way split-K
  {
    const float* __restrict__ w = Wf2 + j;
    float a0 = 0.f, a1 = 0.f;
#pragma unroll
    for (int k = q * 16; k < q * 16 + 16; k += 2) {
      a0 = fmaf(s_u[k], w[(size_t)k * 128], a0);
      a1 = fmaf(s_u[k + 1], w[(size_t)(k + 1) * 128], a1);
    }
    s_red[tid] = a0 + a1;
  }
  __syncthreads();
  if (tid < 128) {
    float v = bf2[tid];
#pragma unroll
    for (int m = 0; m < 8; ++m) v += s_red[tid + 128 * m];
    out[(size_t)b * 128 + tid] = fmaxf(v, 0.f);
  }
}

extern "C" void kernel_launch(void* const* d_in, const int* in_sizes, int n_in,
                              void* d_out, int out_size, void* d_ws, size_t ws_size,
                              hipStream_t stream)
{
  (void)in_sizes; (void)n_in; (void)out_size; (void)ws_size;
  const int*   ids  = (const int*)d_in[0];
  const float* cont = (const float*)d_in[1];
  const int*   edges= (const int*)d_in[2];
  const float* emb  = (const float*)d_in[3];
  const float* W1   = (const float*)d_in[4];
  const float* b1   = (const float*)d_in[5];
  const float* W2   = (const float*)d_in[6];
  const float* b2   = (const float*)d_in[7];
  const float* W3   = (const float*)d_in[8];
  const float* b3   = (const float*)d_in[9];
  const float* W4   = (const float*)d_in[10];
  const float* b4   = (const float*)d_in[11];
  const float* Wf1  = (const float*)d_in[12];
  const float* bf1  = (const float*)d_in[13];
  const float* Wf2  = (const float*)d_in[14];
  const float* bf2  = (const float*)d_in[15];
  float* out = (float*)d_out;

  char* ws = (char*)d_ws;
  size_t off = 0;
  auto alloc = [&](size_t bytes) -> void* {
    void* p = ws + off;
    off = (off + bytes + 255) & ~(size_t)255;
    return p;
  };
  float* dinv     = (float*)alloc((size_t)BB * NN * 4);
  u16*   perm     = (u16*)  alloc((size_t)BB * NPAD * 2);
  u16*   ell      = (u16*)  alloc((size_t)BB * ELLB * 2);
  u16*   elloff   = (u16*)  alloc((size_t)BB * (NT16 + 1) * 2);
  uint2* embh     = (uint2*)alloc((size_t)VOCAB * 64 * 2);
  u32*   yA       = (u32*)  alloc((size_t)BB * NN * 16 * 4);

  hipLaunchKernelGGL(k_setup, dim3(NCONV + BB), dim3(256), 0, stream,
                     emb, embh, edges, dinv, perm, ell, elloff);
  hipLaunchKernelGGL(k_gcn1m, dim3(BB * 6), dim3(256), 0, stream,
                     ids, cont, (const uint4*)embh, W1, dinv, yA);
  hipLaunchKernelGGL(k_fused, dim3(BB), dim3(1024), 0, stream,
                     yA, dinv, perm, ell, elloff,
                     b1, W2, b2, W3, b3, W4, b4, Wf1, bf1, Wf2, bf2, out);
}